// Round 14
// baseline (363.682 us; speedup 1.0000x reference)
//
#include <hip/hip_runtime.h>
#include <cstdint>
#include <cstddef>

typedef _Float16 f16;
typedef __attribute__((ext_vector_type(4))) _Float16 f16x4;
typedef __attribute__((ext_vector_type(8))) _Float16 f16x8;
typedef __attribute__((ext_vector_type(4))) float f32x4;

#define NB 2
#define SEQ 2048
#define DM 2048
#define NH 8
#define HD 256
#define MT (NB * SEQ)   // 4096

// Q pre-scaled by (1/16)*log2(e); exp2 offset 16*log2(e) (fixed-max softmax, exact)
#define QSCALE 0.09016844f
#define CEXP   23.08312065f

// ---------------------------------------------------------------------------
__device__ __forceinline__ void gload16(const f16* g, f16* l) {
    __builtin_amdgcn_global_load_lds(
        (const __attribute__((address_space(1))) uint32_t*)(const void*)g,
        (__attribute__((address_space(3))) uint32_t*)(void*)l,
        16, 0, 0);
}

// ---------------------------------------------------------------------------
// fused f32->f16 conversion of x, Wq, Wk, Wv, Wo in ONE launch.
__global__ __launch_bounds__(256) void k_cvt5(
    const float* __restrict__ x, const float* __restrict__ Wq,
    const float* __restrict__ Wk, const float* __restrict__ Wv,
    const float* __restrict__ Wo,
    f16* __restrict__ xh, f16* __restrict__ Wqh, f16* __restrict__ Wkh,
    f16* __restrict__ Wvh, f16* __restrict__ Woh) {
    const int total = (MT * DM + 4 * DM * DM) / 4;   // f32x4 chunks
    for (int q = blockIdx.x * blockDim.x + threadIdx.x; q < total;
         q += gridDim.x * blockDim.x) {
        int i = q * 4;
        const float* src; f16* dst; int off;
        if (i < MT * DM) { src = x; dst = xh; off = i; }
        else {
            int j = i - MT * DM;
            int w = j >> 22;                 // DM*DM = 2^22
            off = j & ((1 << 22) - 1);
            src = (w == 0) ? Wq : (w == 1) ? Wk : (w == 2) ? Wv : Wo;
            dst = (w == 0) ? Wqh : (w == 1) ? Wkh : (w == 2) ? Wvh : Woh;
        }
        f32x4 v = *(const f32x4*)(src + off);
        f16x4 h;
        h[0] = (f16)v[0]; h[1] = (f16)v[1]; h[2] = (f16)v[2]; h[3] = (f16)v[3];
        *(f16x4*)(dst + off) = h;
    }
}

// ===========================================================================
// 256x128 tile GEMM (unchanged from 350us build): BK=64, 8 waves, 3-buffer
// pipeline, fine 2-phase interleave, vmcnt folded into phase 1.
// ===========================================================================
__device__ __forceinline__ void stage3(const f16* __restrict__ A,
                                       const f16* __restrict__ B,
                                       int m0, int n0, int k0,
                                       f16* AL, f16* BL, int tid, int half) {
#pragma unroll
    for (int jj = 0; jj < 2; ++jj) {
        int j = half * 2 + jj;
        int flat = j * 4096 + tid * 8;
        int r = flat >> 6, c = flat & 63;
        int cs = c ^ ((r & 7) << 3);
        gload16(A + (size_t)(m0 + r) * DM + k0 + cs,
                AL + j * 4096 + (tid >> 6) * 512);
    }
    {
        int j = half;
        int flat = j * 4096 + tid * 8;
        int r = flat >> 6, c = flat & 63;
        int cs = c ^ ((r & 7) << 3);
        gload16(B + (size_t)(n0 + r) * DM + k0 + cs,
                BL + j * 4096 + (tid >> 6) * 512);
    }
}

__device__ __forceinline__ f16x8 rdfrag(const f16* buf, int rowbase, int lr,
                                        int lg, int kk) {
    int row = rowbase + lr;
    int c = (kk * 32 + lg * 8) ^ ((lr & 7) << 3);
    return *(const f16x8*)&buf[row * 64 + c];
}

__device__ __forceinline__ void gemm256x128_core(const f16* __restrict__ A,
                                                 const f16* __restrict__ B,
                                                 int m0, int n0,
                                                 f16* AL, f16* BL,
                                                 f32x4 acc[4][4]) {
    const int tid = threadIdx.x, wave = tid >> 6, lane = tid & 63;
    const int wm = wave >> 1, wn = wave & 1;
    const int lr = lane & 15, lg = lane >> 4;
    const int nt = DM / 64;

    stage3(A, B, m0, n0, 0, AL, BL, tid, 0);
    stage3(A, B, m0, n0, 0, AL, BL, tid, 1);
    stage3(A, B, m0, n0, 64, AL + 16384, BL + 8192, tid, 0);
    stage3(A, B, m0, n0, 64, AL + 16384, BL + 8192, tid, 1);
    asm volatile("s_waitcnt vmcnt(6)" ::: "memory");   // tile 0 landed
    __builtin_amdgcn_s_barrier();
    __builtin_amdgcn_sched_barrier(0);

    for (int kt = 0; kt < nt; ++kt) {
        const f16* Ab = AL + (kt % 3) * 16384;
        const f16* Bb = BL + (kt % 3) * 8192;
        const int arb = wm * 64, brb = wn * 64;

#pragma unroll
        for (int ph = 0; ph < 2; ++ph) {
            f16x8 af[4], bf[4];
#pragma unroll
            for (int mf = 0; mf < 4; ++mf)
                af[mf] = rdfrag(Ab, arb + mf * 16, lr, lg, ph);
#pragma unroll
            for (int nf = 0; nf < 4; ++nf)
                bf[nf] = rdfrag(Bb, brb + nf * 16, lr, lg, ph);

            if (kt + 2 < nt)
                stage3(A, B, m0, n0, (kt + 2) * 64,
                       AL + ((kt + 2) % 3) * 16384,
                       BL + ((kt + 2) % 3) * 8192, tid, ph);

            __builtin_amdgcn_sched_barrier(0);
            if (ph == 1) {
                if (kt + 2 < nt)
                    asm volatile("s_waitcnt vmcnt(6)" ::: "memory");
                else if (kt + 1 < nt)
                    asm volatile("s_waitcnt vmcnt(0)" ::: "memory");
            }
            __builtin_amdgcn_s_barrier();
            asm volatile("s_waitcnt lgkmcnt(0)" ::: "memory");
            __builtin_amdgcn_sched_barrier(0);

            __builtin_amdgcn_s_setprio(1);
#pragma unroll
            for (int mi = 0; mi < 4; ++mi)
#pragma unroll
                for (int nj = 0; nj < 4; ++nj)
                    acc[mi][nj] = __builtin_amdgcn_mfma_f32_16x16x32_f16(
                        af[mi], bf[nj], acc[mi][nj], 0, 0, 0);
            __builtin_amdgcn_s_setprio(0);
            __builtin_amdgcn_s_barrier();
        }
    }
}

// ---------------------------------------------------------------------------
__global__ __launch_bounds__(512, 1) void k_proj_qkv(
    const f16* __restrict__ xh, const f16* __restrict__ Wq,
    const f16* __restrict__ Wk, const f16* __restrict__ Wv,
    const float* __restrict__ bq, const float* __restrict__ bk,
    const float* __restrict__ bv,
    f16* __restrict__ Qh, f16* __restrict__ Kh, f16* __restrict__ Vth) {
    __shared__ __align__(16) f16 AL[3 * 16384];
    __shared__ __align__(16) f16 BL[3 * 8192];
    const int mode = blockIdx.z;
    const f16* W = (mode == 0) ? Wq : (mode == 1) ? Wk : Wv;
    const float* bias = (mode == 0) ? bq : (mode == 1) ? bk : bv;

    const int phys = blockIdx.x + 16 * blockIdx.y;
    const int xcdq = phys & 7, idx = phys >> 3;
    const int m0 = (xcdq * 2 + (idx >> 4)) * 256;
    const int n0 = (idx & 15) * 128;

    f32x4 acc[4][4];
#pragma unroll
    for (int mi = 0; mi < 4; ++mi)
#pragma unroll
        for (int nj = 0; nj < 4; ++nj) acc[mi][nj] = (f32x4){0.f, 0.f, 0.f, 0.f};

    gemm256x128_core(xh, W, m0, n0, AL, BL, acc);

    const int lane = threadIdx.x & 63, wave = threadIdx.x >> 6;
    const int wm = wave >> 1, wn = wave & 1;
    const int lr = lane & 15, lg = lane >> 4;
#pragma unroll
    for (int nj = 0; nj < 4; ++nj) {
        int n = n0 + wn * 64 + nj * 16 + lr;
        float bb = bias[n];
        int h = n >> 8, d = n & 255;
#pragma unroll
        for (int mi = 0; mi < 4; ++mi) {
#pragma unroll
            for (int i = 0; i < 4; ++i) {
                int m = m0 + wm * 64 + mi * 16 + lg * 4 + i;
                int b = m >> 11, s = m & 2047;
                float v = acc[mi][nj][i] + bb;
                size_t bh = (size_t)(b * NH + h);
                if (mode == 0)
                    Qh[((bh * SEQ + s) << 8) + d] = (f16)(v * QSCALE);
                else if (mode == 1)
                    Kh[((bh * SEQ + s) << 8) + d] = (f16)v;
                else
                    Vth[((bh * HD + d) << 11) + s] = (f16)v;
            }
        }
    }
}

// ---------------------------------------------------------------------------
__global__ __launch_bounds__(512, 1) void k_proj_o(
    const f16* __restrict__ Oh, const f16* __restrict__ Wo,
    const float* __restrict__ bo, float* __restrict__ out) {
    __shared__ __align__(16) f16 AL[3 * 16384];
    __shared__ __align__(16) f16 BL[3 * 8192];

    const int phys = blockIdx.x + 16 * blockIdx.y;
    const int xcdq = phys & 7, idx = phys >> 3;
    const int m0 = (xcdq * 2 + (idx >> 4)) * 256;
    const int n0 = (idx & 15) * 128;

    f32x4 acc[4][4];
#pragma unroll
    for (int mi = 0; mi < 4; ++mi)
#pragma unroll
        for (int nj = 0; nj < 4; ++nj) acc[mi][nj] = (f32x4){0.f, 0.f, 0.f, 0.f};

    gemm256x128_core(Oh, Wo, m0, n0, AL, BL, acc);

    const int lane = threadIdx.x & 63, wave = threadIdx.x >> 6;
    const int wm = wave >> 1, wn = wave & 1;
    const int lr = lane & 15, lg = lane >> 4;
#pragma unroll
    for (int nj = 0; nj < 4; ++nj) {
        int n = n0 + wn * 64 + nj * 16 + lr;
        float bb = bo[n];
#pragma unroll
        for (int mi = 0; mi < 4; ++mi) {
#pragma unroll
            for (int i = 0; i < 4; ++i) {
                int m = m0 + wm * 64 + mi * 16 + lg * 4 + i;
                out[(size_t)m * DM + n] = acc[mi][nj][i] + bb;
            }
        }
    }
}

// ---------------------------------------------------------------------------
__device__ __forceinline__ void stageK(const f16* __restrict__ Kb, int kt,
                                       f16* buf, int wave, int lane) {
#pragma unroll
    for (int j = 0; j < 8; ++j) {
        int base = (j * 4 + wave) << 9;
        int flat = base + (lane << 3);
        int r = flat >> 8;
        int c = (flat & 255) ^ ((r & 7) << 3);
        gload16(Kb + (size_t)(kt * 64 + r) * HD + c, buf + base);
    }
}
__device__ __forceinline__ void stageV(const f16* __restrict__ Vb, int kt,
                                       f16* buf, int wave, int lane) {
#pragma unroll
    for (int j = 0; j < 8; ++j) {
        int base = (j * 4 + wave) << 9;
        int flat = base + (lane << 3);
        int rv = flat >> 6;
        int cv = (flat & 63) ^ ((rv & 3) << 3);
        gload16(Vb + ((size_t)rv << 11) + kt * 64 + cv, buf + base);
    }
}

// ---------------------------------------------------------------------------
// Pass A as a standalone K-split reduction: grid (512, 4). Block (bid, chunk)
// computes partial row-sums of exp2(S - CEXP) over tiles t = chunk, chunk+4,...
// Single 32KB K buffer -> ~4 blocks/CU co-resident; 2048 blocks fill tails.
// partial[bh][row][chunk] f32; empty chunks write 0 naturally.
__global__ __launch_bounds__(256, 4) void k_rowsum(
    const f16* __restrict__ Qh, const f16* __restrict__ Kh,
    float* __restrict__ partial) {
    __shared__ __align__(16) f16 Kl[64 * 256];     // 32KB

    const int bid = blockIdx.x;
    const int xcd = bid & 7;
    const int slot = bid >> 3;
    const int psel = slot >> 5;
    const int s5 = slot & 31;
    const int qb = psel ? s5 : (31 - s5);
    const int bhid = xcd * 2 + psel;
    const int chunk = blockIdx.y;

    const int q0 = qb * 64;
    const int tid = threadIdx.x, wave = tid >> 6, lane = tid & 63;
    const int lr = lane & 15, lg = lane >> 4;
    const size_t bh = (size_t)bhid;
    const f16* Qb = Qh + (bh << 19);
    const f16* Kb = Kh + (bh << 19);

    const int kswz = (lr & 7) << 3;

    f16x8 aq[8];
    {
        const f16* qrow = Qb + (size_t)(q0 + wave * 16 + lr) * HD + lg * 8;
#pragma unroll
        for (int kk = 0; kk < 8; ++kk) aq[kk] = *(const f16x8*)(qrow + kk * 32);
    }
    const int rowb = q0 + wave * 16 + lg * 4;
    const int nt = qb + 1;

    float psum[4] = {0.f, 0.f, 0.f, 0.f};

    for (int t = chunk; t < nt; t += 4) {
        stageK(Kb, t, Kl, wave, lane);
        asm volatile("s_waitcnt vmcnt(0)" ::: "memory");
        __builtin_amdgcn_s_barrier();
        __builtin_amdgcn_sched_barrier(0);

        f32x4 s[4];
#pragma unroll
        for (int nj = 0; nj < 4; ++nj) s[nj] = (f32x4){0.f, 0.f, 0.f, 0.f};
        __builtin_amdgcn_s_setprio(1);
#pragma unroll
        for (int kk = 0; kk < 8; ++kk) {
#pragma unroll
            for (int nj = 0; nj < 4; ++nj) {
                f16x8 bk = *(const f16x8*)&Kl[(nj * 16 + lr) * 256 +
                                              ((kk * 32 + lg * 8) ^ kswz)];
                s[nj] = __builtin_amdgcn_mfma_f32_16x16x32_f16(aq[kk], bk, s[nj], 0, 0, 0);
            }
        }
        __builtin_amdgcn_s_setprio(0);
        if (t < qb) {
#pragma unroll
            for (int i = 0; i < 4; ++i)
#pragma unroll
                for (int nj = 0; nj < 4; ++nj)
                    psum[i] += exp2f(s[nj][i] - CEXP);
        } else {
            const int colb = t * 64 + lr;
#pragma unroll
            for (int i = 0; i < 4; ++i) {
                int row = rowb + i;
#pragma unroll
                for (int nj = 0; nj < 4; ++nj)
                    psum[i] += (colb + nj * 16 <= row) ? exp2f(s[nj][i] - CEXP) : 0.f;
            }
        }
        asm volatile("" ::: "memory");
        __builtin_amdgcn_s_barrier();
        __builtin_amdgcn_sched_barrier(0);
    }

#pragma unroll
    for (int i = 0; i < 4; ++i) {
        float l = psum[i];
        l += __shfl_xor(l, 1);
        l += __shfl_xor(l, 2);
        l += __shfl_xor(l, 4);
        l += __shfl_xor(l, 8);
        if (lr == 0)
            partial[((bh * SEQ) + rowb + i) * 4 + chunk] = l;
    }
}

// ---------------------------------------------------------------------------
// Pass B only (R13's measured-best pipeline): reads precomputed partials,
// writes normalized P directly + O. Diagonal-only masking fast path.
__global__ __launch_bounds__(256, 2) void k_attn(
    const f16* __restrict__ Qh, const f16* __restrict__ Kh,
    const f16* __restrict__ Vth, const float* __restrict__ partial,
    float* __restrict__ P, f16* __restrict__ Oh) {
    __shared__ __align__(16) f16 B0[64 * 256];     // 32KB
    __shared__ __align__(16) f16 B1[64 * 256];     // 32KB
    __shared__ __align__(16) f16 Ps[4][16][72];    // per-wave P tile (pad 8)

    const int bid = blockIdx.x;
    const int xcd = bid & 7;
    const int slot = bid >> 3;
    const int psel = slot >> 5;
    const int s5 = slot & 31;
    const int qb = psel ? s5 : (31 - s5);
    const int bhid = xcd * 2 + psel;
    const int b = bhid >> 3, h = bhid & 7;

    const int q0 = qb * 64;
    const int tid = threadIdx.x, wave = tid >> 6, lane = tid & 63;
    const int lr = lane & 15, lg = lane >> 4;
    const size_t bh = (size_t)bhid;
    const f16* Qb = Qh + (bh << 19);
    const f16* Kb = Kh + (bh << 19);
    const f16* Vb = Vth + (bh << 19);
    float* Pb = P + (bh << 22);

    const int kswz = (lr & 7) << 3;
    const int vswz = (lr & 3) << 3;

    f16x8 aq[8];
    {
        const f16* qrow = Qb + (size_t)(q0 + wave * 16 + lr) * HD + lg * 8;
#pragma unroll
        for (int kk = 0; kk < 8; ++kk) aq[kk] = *(const f16x8*)(qrow + kk * 32);
    }

    const int rowb = q0 + wave * 16 + lg * 4;
    const int nt = qb + 1;

    // row inverse sums from k_rowsum partials
    float inv[4];
#pragma unroll
    for (int i = 0; i < 4; ++i) {
        f32x4 p = *(const f32x4*)&partial[((bh * SEQ) + rowb + i) * 4];
        inv[i] = 1.f / (p[0] + p[1] + p[2] + p[3]);
    }

    f32x4 o[16];
#pragma unroll
    for (int n = 0; n < 16; ++n) o[n] = (f32x4){0.f, 0.f, 0.f, 0.f};

    // ---------------- pipelined P write + O accumulate ----------------
    stageK(Kb, 0, B0, wave, lane);             // prefetch K[0]
    for (int kt = 0; kt < nt; ++kt) {
        stageV(Vb, kt, B1, wave, lane);        // V flies under QK^T
        // steady state queue: K[kt](8) + P-stores(2) + V[kt](8) -> <=10 drains K
        if (kt == 0) asm volatile("s_waitcnt vmcnt(8)" ::: "memory");
        else         asm volatile("s_waitcnt vmcnt(10)" ::: "memory");
        __builtin_amdgcn_s_barrier();
        __builtin_amdgcn_sched_barrier(0);

        f32x4 s[4];
#pragma unroll
        for (int nj = 0; nj < 4; ++nj) s[nj] = (f32x4){0.f, 0.f, 0.f, 0.f};
        __builtin_amdgcn_s_setprio(1);
#pragma unroll
        for (int kk = 0; kk < 8; ++kk) {
#pragma unroll
            for (int nj = 0; nj < 4; ++nj) {
                f16x8 bk = *(const f16x8*)&B0[(nj * 16 + lr) * 256 +
                                              ((kk * 32 + lg * 8) ^ kswz)];
                s[nj] = __builtin_amdgcn_mfma_f32_16x16x32_f16(aq[kk], bk, s[nj], 0, 0, 0);
            }
        }
        __builtin_amdgcn_s_setprio(0);
        if (kt < qb) {
#pragma unroll
            for (int i = 0; i < 4; ++i)
#pragma unroll
                for (int nj = 0; nj < 4; ++nj) {
                    float pv = exp2f(s[nj][i] - CEXP) * inv[i];
                    Ps[wave][lg * 4 + i][nj * 16 + lr] = (f16)pv;
                }
        } else {
#pragma unroll
            for (int i = 0; i < 4; ++i) {
                int row = rowb + i;
#pragma unroll
                for (int nj = 0; nj < 4; ++nj) {
                    int col = kt * 64 + nj * 16 + lr;
                    float pv = (col <= row) ? exp2f(s[nj][i] - CEXP) * inv[i] : 0.f;
                    Ps[wave][lg * 4 + i][nj * 16 + lr] = (f16)pv;
                }
            }
        }
        asm volatile("s_waitcnt vmcnt(0)" ::: "memory");  // V landed
        __builtin_amdgcn_s_barrier();                     // + all B0 reads done
        __builtin_amdgcn_sched_barrier(0);

        if (kt + 1 < nt) stageK(Kb, kt + 1, B0, wave, lane);  // flies under PV

        // PV accumulate first (stores issue last, off the critical path)
        __builtin_amdgcn_s_setprio(1);
#pragma unroll
        for (int kk2 = 0; kk2 < 2; ++kk2) {
            f16x8 pa = *(const f16x8*)&Ps[wave][lr][kk2 * 32 + lg * 8];
#pragma unroll
            for (int n = 0; n < 16; ++n) {
                f16x8 bv = *(const f16x8*)&B1[(n * 16 + lr) * 64 +
                                              ((kk2 * 32 + lg * 8) ^ vswz)];
                o[n] = __builtin_amdgcn_mfma_f32_16x16x32_f16(pa, bv, o[n], 0, 0, 0);
            }
        }
        __builtin_amdgcn_s_setprio(0);

        // wide normalized-P store (f16 -> f32) from Ps
#pragma unroll
        for (int h2 = 0; h2 < 2; ++h2) {
            int rr = h2 * 8 + (lane >> 3);
            int cc = (lane & 7) * 8;
            f16x8 ph = *(const f16x8*)&Ps[wave][rr][cc];
            int row = q0 + wave * 16 + rr;
            float* dst = Pb + (size_t)row * SEQ + kt * 64 + cc;
            f32x4 lo = {(float)ph[0], (float)ph[1], (float)ph[2], (float)ph[3]};
            f32x4 hi = {(float)ph[4], (float)ph[5], (float)ph[6], (float)ph[7]};
            *(f32x4*)dst = lo;
            *(f32x4*)(dst + 4) = hi;
        }

        asm volatile("" ::: "memory");
        __builtin_amdgcn_s_barrier();          // B1/Ps reads done before next stage
        __builtin_amdgcn_sched_barrier(0);
    }

    // zero-fill strictly-masked P region
    int kstart = (qb + 1) * 64;
    if (kstart < SEQ) {
        f32x4 z = (f32x4){0.f, 0.f, 0.f, 0.f};
        for (int r = 0; r < 64; ++r) {
            float* rp = Pb + (size_t)(q0 + r) * SEQ;
            for (int c = kstart + tid * 4; c < SEQ; c += 1024)
                *(f32x4*)(rp + c) = z;
        }
    }

    // write O (f16) to [b, s, h*HD + d]
#pragma unroll
    for (int n = 0; n < 16; ++n) {
#pragma unroll
        for (int i = 0; i < 4; ++i) {
            int row = rowb + i;
            int d = n * 16 + lr;
            Oh[((size_t)b * SEQ + row) * DM + h * HD + d] = (f16)o[n][i];
        }
    }
}

// ---------------------------------------------------------------------------
extern "C" void kernel_launch(void* const* d_in, const int* in_sizes, int n_in,
                              void* d_out, int out_size, void* d_ws, size_t ws_size,
                              hipStream_t stream) {
    const float* x  = (const float*)d_in[0];
    const float* Wq = (const float*)d_in[1];
    const float* bq = (const float*)d_in[2];
    const float* Wk = (const float*)d_in[3];
    const float* bk = (const float*)d_in[4];
    const float* Wv = (const float*)d_in[5];
    const float* bv = (const float*)d_in[6];
    const float* Wo = (const float*)d_in[7];
    const float* bo = (const float*)d_in[8];

    float* out  = (float*)d_out;
    float* Pout = out + (size_t)MT * DM;

    // f16 conversion scratch parked in the not-yet-written P region
    f16* xh  = (f16*)Pout;
    f16* Wqh = xh + (size_t)MT * DM;
    f16* Wkh = Wqh + (size_t)DM * DM;
    f16* Wvh = Wkh + (size_t)DM * DM;

    // persistent scratch in ws
    f16* ws16 = (f16*)d_ws;
    f16* Woh = ws16;                               // 4194304 f16
    f16* Qh  = Woh + (size_t)DM * DM;              // 8388608
    f16* Kh  = Qh + (size_t)8388608;
    f16* Vth = Kh + (size_t)8388608;
    f16* Oh  = Vth + (size_t)8388608;
    float* partial = (float*)(Oh + (size_t)8388608);   // 16*2048*4 f32 = 512KB
    if (ws_size < (size_t)(4194304 + 4 * 8388608) * sizeof(f16) + 524288) return;

    // fused conversions (single launch)
    k_cvt5<<<2048, 256, 0, stream>>>(x, Wq, Wk, Wv, Wo, xh, Wqh, Wkh, Wvh, Woh);

    // QKV projections: 16 x 16 x 3 = 768 blocks (3/CU exact)
    dim3 g1(DM / 128, MT / 256, 3);
    k_proj_qkv<<<g1, 512, 0, stream>>>(xh, Wqh, Wkh, Wvh, bq, bk, bv, Qh, Kh, Vth);

    // K-split softmax row-sums (pass A at 4x parallelism)
    k_rowsum<<<dim3(512, 4), 256, 0, stream>>>(Qh, Kh, partial);

    // pass-B-only fused attention (XCD-locality 1D grid)
    k_attn<<<dim3(512), 256, 0, stream>>>(Qh, Kh, Vth, partial, Pout, Oh);

    // output projection: 16 x 16 = 256 blocks (1/CU exact)
    dim3 g3(DM / 128, MT / 256, 1);
    k_proj_o<<<g3, 512, 0, stream>>>(Oh, Woh, bo, out);
}

// Round 15
// 348.690 us; speedup vs baseline: 1.0430x; 1.0430x over previous
//
#include <hip/hip_runtime.h>
#include <cstdint>
#include <cstddef>

typedef _Float16 f16;
typedef __attribute__((ext_vector_type(4))) _Float16 f16x4;
typedef __attribute__((ext_vector_type(8))) _Float16 f16x8;
typedef __attribute__((ext_vector_type(4))) float f32x4;

#define NB 2
#define SEQ 2048
#define DM 2048
#define NH 8
#define HD 256
#define MT (NB * SEQ)   // 4096

// Q pre-scaled by (1/16)*log2(e); exp2 offset 16*log2(e) (fixed-max softmax, exact)
#define QSCALE 0.09016844f
#define CEXP   23.08312065f

// ---------------------------------------------------------------------------
__device__ __forceinline__ void gload16(const f16* g, f16* l) {
    __builtin_amdgcn_global_load_lds(
        (const __attribute__((address_space(1))) uint32_t*)(const void*)g,
        (__attribute__((address_space(3))) uint32_t*)(void*)l,
        16, 0, 0);
}

// ---------------------------------------------------------------------------
// fused f32->f16 conversion of x, Wq, Wk, Wv, Wo in ONE launch.
__global__ __launch_bounds__(256) void k_cvt5(
    const float* __restrict__ x, const float* __restrict__ Wq,
    const float* __restrict__ Wk, const float* __restrict__ Wv,
    const float* __restrict__ Wo,
    f16* __restrict__ xh, f16* __restrict__ Wqh, f16* __restrict__ Wkh,
    f16* __restrict__ Wvh, f16* __restrict__ Woh) {
    const int total = (MT * DM + 4 * DM * DM) / 4;   // f32x4 chunks
    for (int q = blockIdx.x * blockDim.x + threadIdx.x; q < total;
         q += gridDim.x * blockDim.x) {
        int i = q * 4;
        const float* src; f16* dst; int off;
        if (i < MT * DM) { src = x; dst = xh; off = i; }
        else {
            int j = i - MT * DM;
            int w = j >> 22;                 // DM*DM = 2^22
            off = j & ((1 << 22) - 1);
            src = (w == 0) ? Wq : (w == 1) ? Wk : (w == 2) ? Wv : Wo;
            dst = (w == 0) ? Wqh : (w == 1) ? Wkh : (w == 2) ? Wvh : Woh;
        }
        f32x4 v = *(const f32x4*)(src + off);
        f16x4 h;
        h[0] = (f16)v[0]; h[1] = (f16)v[1]; h[2] = (f16)v[2]; h[3] = (f16)v[3];
        *(f16x4*)(dst + off) = h;
    }
}

// ===========================================================================
// 256x128 tile GEMM: BK=64, 8 waves, 3-buffer pipeline, fine 2-phase
// interleave, vmcnt folded into phase 1.
// ===========================================================================
__device__ __forceinline__ void stage3(const f16* __restrict__ A,
                                       const f16* __restrict__ B,
                                       int m0, int n0, int k0,
                                       f16* AL, f16* BL, int tid, int half) {
#pragma unroll
    for (int jj = 0; jj < 2; ++jj) {
        int j = half * 2 + jj;
        int flat = j * 4096 + tid * 8;
        int r = flat >> 6, c = flat & 63;
        int cs = c ^ ((r & 7) << 3);
        gload16(A + (size_t)(m0 + r) * DM + k0 + cs,
                AL + j * 4096 + (tid >> 6) * 512);
    }
    {
        int j = half;
        int flat = j * 4096 + tid * 8;
        int r = flat >> 6, c = flat & 63;
        int cs = c ^ ((r & 7) << 3);
        gload16(B + (size_t)(n0 + r) * DM + k0 + cs,
                BL + j * 4096 + (tid >> 6) * 512);
    }
}

__device__ __forceinline__ f16x8 rdfrag(const f16* buf, int rowbase, int lr,
                                        int lg, int kk) {
    int row = rowbase + lr;
    int c = (kk * 32 + lg * 8) ^ ((lr & 7) << 3);
    return *(const f16x8*)&buf[row * 64 + c];
}

__device__ __forceinline__ void gemm256x128_core(const f16* __restrict__ A,
                                                 const f16* __restrict__ B,
                                                 int m0, int n0,
                                                 f16* AL, f16* BL,
                                                 f32x4 acc[4][4]) {
    const int tid = threadIdx.x, wave = tid >> 6, lane = tid & 63;
    const int wm = wave >> 1, wn = wave & 1;
    const int lr = lane & 15, lg = lane >> 4;
    const int nt = DM / 64;

    stage3(A, B, m0, n0, 0, AL, BL, tid, 0);
    stage3(A, B, m0, n0, 0, AL, BL, tid, 1);
    stage3(A, B, m0, n0, 64, AL + 16384, BL + 8192, tid, 0);
    stage3(A, B, m0, n0, 64, AL + 16384, BL + 8192, tid, 1);
    asm volatile("s_waitcnt vmcnt(6)" ::: "memory");   // tile 0 landed
    __builtin_amdgcn_s_barrier();
    __builtin_amdgcn_sched_barrier(0);

    for (int kt = 0; kt < nt; ++kt) {
        const f16* Ab = AL + (kt % 3) * 16384;
        const f16* Bb = BL + (kt % 3) * 8192;
        const int arb = wm * 64, brb = wn * 64;

#pragma unroll
        for (int ph = 0; ph < 2; ++ph) {
            f16x8 af[4], bf[4];
#pragma unroll
            for (int mf = 0; mf < 4; ++mf)
                af[mf] = rdfrag(Ab, arb + mf * 16, lr, lg, ph);
#pragma unroll
            for (int nf = 0; nf < 4; ++nf)
                bf[nf] = rdfrag(Bb, brb + nf * 16, lr, lg, ph);

            if (kt + 2 < nt)
                stage3(A, B, m0, n0, (kt + 2) * 64,
                       AL + ((kt + 2) % 3) * 16384,
                       BL + ((kt + 2) % 3) * 8192, tid, ph);

            __builtin_amdgcn_sched_barrier(0);
            if (ph == 1) {
                if (kt + 2 < nt)
                    asm volatile("s_waitcnt vmcnt(6)" ::: "memory");
                else if (kt + 1 < nt)
                    asm volatile("s_waitcnt vmcnt(0)" ::: "memory");
            }
            __builtin_amdgcn_s_barrier();
            asm volatile("s_waitcnt lgkmcnt(0)" ::: "memory");
            __builtin_amdgcn_sched_barrier(0);

            __builtin_amdgcn_s_setprio(1);
#pragma unroll
            for (int mi = 0; mi < 4; ++mi)
#pragma unroll
                for (int nj = 0; nj < 4; ++nj)
                    acc[mi][nj] = __builtin_amdgcn_mfma_f32_16x16x32_f16(
                        af[mi], bf[nj], acc[mi][nj], 0, 0, 0);
            __builtin_amdgcn_s_setprio(0);
            __builtin_amdgcn_s_barrier();
        }
    }
}

// ---------------------------------------------------------------------------
__global__ __launch_bounds__(512, 1) void k_proj_qkv(
    const f16* __restrict__ xh, const f16* __restrict__ Wq,
    const f16* __restrict__ Wk, const f16* __restrict__ Wv,
    const float* __restrict__ bq, const float* __restrict__ bk,
    const float* __restrict__ bv,
    f16* __restrict__ Qh, f16* __restrict__ Kh, f16* __restrict__ Vth) {
    __shared__ __align__(16) f16 AL[3 * 16384];
    __shared__ __align__(16) f16 BL[3 * 8192];
    const int mode = blockIdx.z;
    const f16* W = (mode == 0) ? Wq : (mode == 1) ? Wk : Wv;
    const float* bias = (mode == 0) ? bq : (mode == 1) ? bk : bv;

    const int phys = blockIdx.x + 16 * blockIdx.y;
    const int xcdq = phys & 7, idx = phys >> 3;
    const int m0 = (xcdq * 2 + (idx >> 4)) * 256;
    const int n0 = (idx & 15) * 128;

    f32x4 acc[4][4];
#pragma unroll
    for (int mi = 0; mi < 4; ++mi)
#pragma unroll
        for (int nj = 0; nj < 4; ++nj) acc[mi][nj] = (f32x4){0.f, 0.f, 0.f, 0.f};

    gemm256x128_core(xh, W, m0, n0, AL, BL, acc);

    const int lane = threadIdx.x & 63, wave = threadIdx.x >> 6;
    const int wm = wave >> 1, wn = wave & 1;
    const int lr = lane & 15, lg = lane >> 4;
#pragma unroll
    for (int nj = 0; nj < 4; ++nj) {
        int n = n0 + wn * 64 + nj * 16 + lr;
        float bb = bias[n];
        int h = n >> 8, d = n & 255;
#pragma unroll
        for (int mi = 0; mi < 4; ++mi) {
#pragma unroll
            for (int i = 0; i < 4; ++i) {
                int m = m0 + wm * 64 + mi * 16 + lg * 4 + i;
                int b = m >> 11, s = m & 2047;
                float v = acc[mi][nj][i] + bb;
                size_t bh = (size_t)(b * NH + h);
                if (mode == 0)
                    Qh[((bh * SEQ + s) << 8) + d] = (f16)(v * QSCALE);
                else if (mode == 1)
                    Kh[((bh * SEQ + s) << 8) + d] = (f16)v;
                else
                    Vth[((bh * HD + d) << 11) + s] = (f16)v;
            }
        }
    }
}

// ---------------------------------------------------------------------------
__global__ __launch_bounds__(512, 1) void k_proj_o(
    const f16* __restrict__ Oh, const f16* __restrict__ Wo,
    const float* __restrict__ bo, float* __restrict__ out) {
    __shared__ __align__(16) f16 AL[3 * 16384];
    __shared__ __align__(16) f16 BL[3 * 8192];

    const int phys = blockIdx.x + 16 * blockIdx.y;
    const int xcdq = phys & 7, idx = phys >> 3;
    const int m0 = (xcdq * 2 + (idx >> 4)) * 256;
    const int n0 = (idx & 15) * 128;

    f32x4 acc[4][4];
#pragma unroll
    for (int mi = 0; mi < 4; ++mi)
#pragma unroll
        for (int nj = 0; nj < 4; ++nj) acc[mi][nj] = (f32x4){0.f, 0.f, 0.f, 0.f};

    gemm256x128_core(Oh, Wo, m0, n0, AL, BL, acc);

    const int lane = threadIdx.x & 63, wave = threadIdx.x >> 6;
    const int wm = wave >> 1, wn = wave & 1;
    const int lr = lane & 15, lg = lane >> 4;
#pragma unroll
    for (int nj = 0; nj < 4; ++nj) {
        int n = n0 + wn * 64 + nj * 16 + lr;
        float bb = bo[n];
#pragma unroll
        for (int mi = 0; mi < 4; ++mi) {
#pragma unroll
            for (int i = 0; i < 4; ++i) {
                int m = m0 + wm * 64 + mi * 16 + lg * 4 + i;
                out[(size_t)m * DM + n] = acc[mi][nj][i] + bb;
            }
        }
    }
}

// ---------------------------------------------------------------------------
__device__ __forceinline__ void stageK(const f16* __restrict__ Kb, int kt,
                                       f16* buf, int wave, int lane) {
#pragma unroll
    for (int j = 0; j < 8; ++j) {
        int base = (j * 4 + wave) << 9;
        int flat = base + (lane << 3);
        int r = flat >> 8;
        int c = (flat & 255) ^ ((r & 7) << 3);
        gload16(Kb + (size_t)(kt * 64 + r) * HD + c, buf + base);
    }
}
__device__ __forceinline__ void stageV(const f16* __restrict__ Vb, int kt,
                                       f16* buf, int wave, int lane) {
#pragma unroll
    for (int j = 0; j < 8; ++j) {
        int base = (j * 4 + wave) << 9;
        int flat = base + (lane << 3);
        int rv = flat >> 6;
        int cv = (flat & 63) ^ ((rv & 3) << 3);
        gload16(Vb + ((size_t)rv << 11) + kt * 64 + cv, buf + base);
    }
}

// ---------------------------------------------------------------------------
// Two-pass fused causal attention (measured-best), with wave-uniform
// diagonal-only masking fast path.
__global__ __launch_bounds__(256, 2) void k_attn(
    const f16* __restrict__ Qh, const f16* __restrict__ Kh,
    const f16* __restrict__ Vth, float* __restrict__ P,
    f16* __restrict__ Oh) {
    __shared__ __align__(16) f16 B0[64 * 256];     // 32KB
    __shared__ __align__(16) f16 B1[64 * 256];     // 32KB
    __shared__ __align__(16) f16 Ps[4][16][72];    // per-wave P tile (pad 8)

    const int bid = blockIdx.x;
    const int xcd = bid & 7;
    const int slot = bid >> 3;
    const int psel = slot >> 5;
    const int s5 = slot & 31;
    const int qb = psel ? s5 : (31 - s5);
    const int bhid = xcd * 2 + psel;
    const int b = bhid >> 3, h = bhid & 7;

    const int q0 = qb * 64;
    const int tid = threadIdx.x, wave = tid >> 6, lane = tid & 63;
    const int lr = lane & 15, lg = lane >> 4;
    const size_t bh = (size_t)bhid;
    const f16* Qb = Qh + (bh << 19);
    const f16* Kb = Kh + (bh << 19);
    const f16* Vb = Vth + (bh << 19);
    float* Pb = P + (bh << 22);

    const int kswz = (lr & 7) << 3;
    const int vswz = (lr & 3) << 3;

    f16x8 aq[8];
    {
        const f16* qrow = Qb + (size_t)(q0 + wave * 16 + lr) * HD + lg * 8;
#pragma unroll
        for (int kk = 0; kk < 8; ++kk) aq[kk] = *(const f16x8*)(qrow + kk * 32);
    }

    const int rowb = q0 + wave * 16 + lg * 4;
    const int nt = qb + 1;

    float psum[4] = {0.f, 0.f, 0.f, 0.f};

    // ---------------- PASS A: row sums, counted-vmcnt K dbuf ----------------
    stageK(Kb, 0, B0, wave, lane);
    for (int kt = 0; kt < nt; ++kt) {
        f16* cur = (kt & 1) ? B1 : B0;
        f16* nxt = (kt & 1) ? B0 : B1;
        if (kt + 1 < nt) {
            stageK(Kb, kt + 1, nxt, wave, lane);
            asm volatile("s_waitcnt vmcnt(8)" ::: "memory");   // K[kt] landed
        } else {
            asm volatile("s_waitcnt vmcnt(0)" ::: "memory");
        }
        __builtin_amdgcn_s_barrier();
        __builtin_amdgcn_sched_barrier(0);

        f32x4 s[4];
#pragma unroll
        for (int nj = 0; nj < 4; ++nj) s[nj] = (f32x4){0.f, 0.f, 0.f, 0.f};
        __builtin_amdgcn_s_setprio(1);
#pragma unroll
        for (int kk = 0; kk < 8; ++kk) {
#pragma unroll
            for (int nj = 0; nj < 4; ++nj) {
                f16x8 bk = *(const f16x8*)&cur[(nj * 16 + lr) * 256 +
                                               ((kk * 32 + lg * 8) ^ kswz)];
                s[nj] = __builtin_amdgcn_mfma_f32_16x16x32_f16(aq[kk], bk, s[nj], 0, 0, 0);
            }
        }
        __builtin_amdgcn_s_setprio(0);
        if (kt < qb) {
            // fully-unmasked tile: no compares needed
#pragma unroll
            for (int i = 0; i < 4; ++i)
#pragma unroll
                for (int nj = 0; nj < 4; ++nj)
                    psum[i] += exp2f(s[nj][i] - CEXP);
        } else {
            const int colb = kt * 64 + lr;
#pragma unroll
            for (int i = 0; i < 4; ++i) {
                int row = rowb + i;
#pragma unroll
                for (int nj = 0; nj < 4; ++nj)
                    psum[i] += (colb + nj * 16 <= row) ? exp2f(s[nj][i] - CEXP) : 0.f;
            }
        }
        asm volatile("" ::: "memory");
        __builtin_amdgcn_s_barrier();
        __builtin_amdgcn_sched_barrier(0);
    }

    float inv[4];
#pragma unroll
    for (int i = 0; i < 4; ++i) {
        float l = psum[i];
        l += __shfl_xor(l, 1);
        l += __shfl_xor(l, 2);
        l += __shfl_xor(l, 4);
        l += __shfl_xor(l, 8);
        inv[i] = 1.f / l;
    }

    f32x4 o[16];
#pragma unroll
    for (int n = 0; n < 16; ++n) o[n] = (f32x4){0.f, 0.f, 0.f, 0.f};

    // ---------------- PASS B: pipelined P write + O accumulate --------------
    stageK(Kb, 0, B0, wave, lane);             // prefetch K[0]
    for (int kt = 0; kt < nt; ++kt) {
        stageV(Vb, kt, B1, wave, lane);        // V flies under QK^T
        // steady state queue: K[kt](8) + P-stores(2) + V[kt](8) -> <=10 drains K
        if (kt == 0) asm volatile("s_waitcnt vmcnt(8)" ::: "memory");
        else         asm volatile("s_waitcnt vmcnt(10)" ::: "memory");
        __builtin_amdgcn_s_barrier();
        __builtin_amdgcn_sched_barrier(0);

        f32x4 s[4];
#pragma unroll
        for (int nj = 0; nj < 4; ++nj) s[nj] = (f32x4){0.f, 0.f, 0.f, 0.f};
        __builtin_amdgcn_s_setprio(1);
#pragma unroll
        for (int kk = 0; kk < 8; ++kk) {
#pragma unroll
            for (int nj = 0; nj < 4; ++nj) {
                f16x8 bk = *(const f16x8*)&B0[(nj * 16 + lr) * 256 +
                                              ((kk * 32 + lg * 8) ^ kswz)];
                s[nj] = __builtin_amdgcn_mfma_f32_16x16x32_f16(aq[kk], bk, s[nj], 0, 0, 0);
            }
        }
        __builtin_amdgcn_s_setprio(0);
        if (kt < qb) {
#pragma unroll
            for (int i = 0; i < 4; ++i)
#pragma unroll
                for (int nj = 0; nj < 4; ++nj) {
                    float pv = exp2f(s[nj][i] - CEXP) * inv[i];
                    Ps[wave][lg * 4 + i][nj * 16 + lr] = (f16)pv;
                }
        } else {
#pragma unroll
            for (int i = 0; i < 4; ++i) {
                int row = rowb + i;
#pragma unroll
                for (int nj = 0; nj < 4; ++nj) {
                    int col = kt * 64 + nj * 16 + lr;
                    float pv = (col <= row) ? exp2f(s[nj][i] - CEXP) * inv[i] : 0.f;
                    Ps[wave][lg * 4 + i][nj * 16 + lr] = (f16)pv;
                }
            }
        }
        asm volatile("s_waitcnt vmcnt(0)" ::: "memory");  // V landed
        __builtin_amdgcn_s_barrier();                     // + all B0 reads done
        __builtin_amdgcn_sched_barrier(0);

        if (kt + 1 < nt) stageK(Kb, kt + 1, B0, wave, lane);  // flies under PV

        // PV accumulate first (stores issue last, off the critical path)
        __builtin_amdgcn_s_setprio(1);
#pragma unroll
        for (int kk2 = 0; kk2 < 2; ++kk2) {
            f16x8 pa = *(const f16x8*)&Ps[wave][lr][kk2 * 32 + lg * 8];
#pragma unroll
            for (int n = 0; n < 16; ++n) {
                f16x8 bv = *(const f16x8*)&B1[(n * 16 + lr) * 64 +
                                              ((kk2 * 32 + lg * 8) ^ vswz)];
                o[n] = __builtin_amdgcn_mfma_f32_16x16x32_f16(pa, bv, o[n], 0, 0, 0);
            }
        }
        __builtin_amdgcn_s_setprio(0);

        // wide normalized-P store (f16 -> f32) from Ps
#pragma unroll
        for (int h2 = 0; h2 < 2; ++h2) {
            int rr = h2 * 8 + (lane >> 3);
            int cc = (lane & 7) * 8;
            f16x8 ph = *(const f16x8*)&Ps[wave][rr][cc];
            int row = q0 + wave * 16 + rr;
            float* dst = Pb + (size_t)row * SEQ + kt * 64 + cc;
            f32x4 lo = {(float)ph[0], (float)ph[1], (float)ph[2], (float)ph[3]};
            f32x4 hi = {(float)ph[4], (float)ph[5], (float)ph[6], (float)ph[7]};
            *(f32x4*)dst = lo;
            *(f32x4*)(dst + 4) = hi;
        }

        asm volatile("" ::: "memory");
        __builtin_amdgcn_s_barrier();          // B1/Ps reads done before next stage
        __builtin_amdgcn_sched_barrier(0);
    }

    // zero-fill strictly-masked P region
    int kstart = (qb + 1) * 64;
    if (kstart < SEQ) {
        f32x4 z = (f32x4){0.f, 0.f, 0.f, 0.f};
        for (int r = 0; r < 64; ++r) {
            float* rp = Pb + (size_t)(q0 + r) * SEQ;
            for (int c = kstart + tid * 4; c < SEQ; c += 1024)
                *(f32x4*)(rp + c) = z;
        }
    }

    // write O (f16) to [b, s, h*HD + d]
#pragma unroll
    for (int n = 0; n < 16; ++n) {
#pragma unroll
        for (int i = 0; i < 4; ++i) {
            int row = rowb + i;
            int d = n * 16 + lr;
            Oh[((size_t)b * SEQ + row) * DM + h * HD + d] = (f16)o[n][i];
        }
    }
}

// ---------------------------------------------------------------------------
extern "C" void kernel_launch(void* const* d_in, const int* in_sizes, int n_in,
                              void* d_out, int out_size, void* d_ws, size_t ws_size,
                              hipStream_t stream) {
    const float* x  = (const float*)d_in[0];
    const float* Wq = (const float*)d_in[1];
    const float* bq = (const float*)d_in[2];
    const float* Wk = (const float*)d_in[3];
    const float* bk = (const float*)d_in[4];
    const float* Wv = (const float*)d_in[5];
    const float* bv = (const float*)d_in[6];
    const float* Wo = (const float*)d_in[7];
    const float* bo = (const float*)d_in[8];

    float* out  = (float*)d_out;
    float* Pout = out + (size_t)MT * DM;

    // f16 conversion scratch parked in the not-yet-written P region
    f16* xh  = (f16*)Pout;
    f16* Wqh = xh + (size_t)MT * DM;
    f16* Wkh = Wqh + (size_t)DM * DM;
    f16* Wvh = Wkh + (size_t)DM * DM;

    // persistent scratch in ws
    f16* ws16 = (f16*)d_ws;
    f16* Woh = ws16;                               // 4194304 f16
    f16* Qh  = Woh + (size_t)DM * DM;              // 8388608
    f16* Kh  = Qh + (size_t)8388608;
    f16* Vth = Kh + (size_t)8388608;
    f16* Oh  = Vth + (size_t)8388608;
    if (ws_size < (size_t)(4194304 + 4 * 8388608) * sizeof(f16)) return;

    // fused conversions (single launch)
    k_cvt5<<<2048, 256, 0, stream>>>(x, Wq, Wk, Wv, Wo, xh, Wqh, Wkh, Wvh, Woh);

    // QKV projections: 16 x 16 x 3 = 768 blocks (3/CU exact)
    dim3 g1(DM / 128, MT / 256, 3);
    k_proj_qkv<<<g1, 512, 0, stream>>>(xh, Wqh, Wkh, Wvh, bq, bk, bv, Qh, Kh, Vth);

    // two-pass fused attention (XCD-locality 1D grid)
    k_attn<<<dim3(512), 256, 0, stream>>>(Qh, Kh, Vth, Pout, Oh);

    // output projection: 16 x 16 = 256 blocks (1/CU exact)
    dim3 g3(DM / 128, MT / 256, 1);
    k_proj_o<<<g3, 512, 0, stream>>>(Oh, Woh, bo, out);
}